// Round 7
// baseline (249.347 us; speedup 1.0000x reference)
//
#include <hip/hip_runtime.h>
#include <hip/hip_cooperative_groups.h>
#include <math.h>

#define HW 4096
#define CIN 256
#define DD 256
#define M_TOTAL 48
#define NSP 4
#define SPPX (HW / NSP)   // 1024 pixels per spatial slice

namespace cg = cooperative_groups;

// ===========================================================================
// Shared device helpers (identical math in fused and fallback paths)
// ===========================================================================
__device__ __forceinline__ void scatter_block(
    const float* __restrict__ p_motions, float* __restrict__ Ag4,
    float* __restrict__ Sg4, float* Al, float* red, int m, int sp, int tid)
{
    const float4* p0 = (const float4*)(p_motions + (size_t)m * 2 * 65536); // dy
    const float4* p1 = p0 + 65536 / 4;                                     // dx

    for (int i = tid; i < HW; i += 256) Al[i] = 0.f;
    __syncthreads();

    #pragma unroll
    for (int ii = 0; ii < SPPX / 256; ++ii) {
        const int i = ii * 256 + tid;
        const int y = sp * 16 + (i >> 6);
        const int x = i & 63;
        const int r1 = 4 * y + 1, r2 = 4 * y + 2;
        // taps at cols 4x+1,4x+2 = elements .y/.z of float4 index x
        const float4 v10 = p0[r1 * 64 + x];
        const float4 v20 = p0[r2 * 64 + x];
        const float4 v11 = p1[r1 * 64 + x];
        const float4 v21 = p1[r2 * 64 + x];
        const float fy = (v10.y + v10.z + v20.y + v20.z) * 0.0625f; // avg*0.25
        const float fx = (v11.y + v11.z + v21.y + v21.z) * 0.0625f;

        const float yy = (float)y + fy;
        const float xx = (float)x + fx;
        const float y0f = floorf(yy), x0f = floorf(xx);
        const float wy = yy - y0f, wx = xx - x0f;
        const int iy0 = (int)y0f, ix0 = (int)x0f;
        const int iy1 = iy0 + 1, ix1 = ix0 + 1;
        const float w00 = (1.f - wy) * (1.f - wx);
        const float w01 = (1.f - wy) * wx;
        const float w10 = wy * (1.f - wx);
        const float w11 = wy * wx;
        const bool y0ok = (iy0 >= 0) & (iy0 < 64);
        const bool y1ok = (iy1 >= 0) & (iy1 < 64);
        const bool x0ok = (ix0 >= 0) & (ix0 < 64);
        const bool x1ok = (ix1 >= 0) & (ix1 < 64);
        if (y0ok & x0ok) atomicAdd(&Al[iy0 * 64 + ix0], w00);
        if (y0ok & x1ok) atomicAdd(&Al[iy0 * 64 + ix1], w01);
        if (y1ok & x0ok) atomicAdd(&Al[iy1 * 64 + ix0], w10);
        if (y1ok & x1ok) atomicAdd(&Al[iy1 * 64 + ix1], w11);
    }
    __syncthreads();

    const float4* Al4 = (const float4*)Al;
    float4* dst = (float4*)(Ag4 + (size_t)(m * NSP + sp) * HW);
    float part = 0.f;
    #pragma unroll
    for (int i = tid; i < HW / 4; i += 256) {
        const float4 v = Al4[i];
        dst[i] = v;
        part += v.x + v.y + v.z + v.w;
    }
    for (int off = 32; off > 0; off >>= 1) part += __shfl_down(part, off, 64);
    if ((tid & 63) == 0) red[tid >> 6] = part;
    __syncthreads();
    if (tid == 0) Sg4[m * NSP + sp] = red[0] + red[1] + red[2] + red[3];
}

__device__ __forceinline__ void fold_block(
    const float* __restrict__ W_emb, const float* __restrict__ b_emb,
    const float* __restrict__ W_dc, float* __restrict__ WT,
    float* __restrict__ bfold, float* __restrict__ out,
    float* Al, float* red, int o, int tid)
{
    Al[tid] = W_dc[(size_t)o * 256 + tid];       // wdc row in LDS
    if (tid < 48) out[(size_t)o * 48 + tid] = 0.f;
    __syncthreads();
    float acc = 0.f;
    #pragma unroll 8
    for (int k = 0; k < 256; ++k)
        acc += Al[k] * W_emb[(size_t)k * 256 + tid];    // coalesced rows
    WT[(size_t)tid * 256 + o] = acc;                    // transposed store

    float pb = Al[tid] * b_emb[tid];
    for (int off = 32; off > 0; off >>= 1) pb += __shfl_down(pb, off, 64);
    if ((tid & 63) == 0) red[tid >> 6] = pb;
    __syncthreads();
    if (tid == 0) bfold[o] = red[0] + red[1] + red[2] + red[3];
}

__device__ __forceinline__ void gather_unit(
    const float* __restrict__ i_features, const float* __restrict__ Ag4,
    const float* __restrict__ Sg4, const float* __restrict__ WT,
    const float* __restrict__ bfold, const float* __restrict__ b_dc,
    float* __restrict__ out, float* gl, int u, int tid, int wave, int lane)
{
    const int gfm = u >> 6;
    const int gchunk = (u >> 2) & 15;
    const int gsp = u & 3;
    const int gm0 = gfm * 3;

    // sum the 4 partial A maps for this slice into registers
    float4 a[3][4];
    #pragma unroll
    for (int j = 0; j < 3; ++j) {
        const float4* P0 = (const float4*)(Ag4 + ((size_t)((gm0 + j) * NSP + 0)) * HW + gsp * SPPX);
        const float4* P1 = (const float4*)(Ag4 + ((size_t)((gm0 + j) * NSP + 1)) * HW + gsp * SPPX);
        const float4* P2 = (const float4*)(Ag4 + ((size_t)((gm0 + j) * NSP + 2)) * HW + gsp * SPPX);
        const float4* P3 = (const float4*)(Ag4 + ((size_t)((gm0 + j) * NSP + 3)) * HW + gsp * SPPX);
        #pragma unroll
        for (int k = 0; k < 4; ++k) {
            const float4 t0 = P0[lane + 64 * k];
            const float4 t1 = P1[lane + 64 * k];
            const float4 t2 = P2[lane + 64 * k];
            const float4 t3 = P3[lane + 64 * k];
            a[j][k].x = t0.x + t1.x + t2.x + t3.x;
            a[j][k].y = t0.y + t1.y + t2.y + t3.y;
            a[j][k].z = t0.z + t1.z + t2.z + t3.z;
            a[j][k].w = t0.w + t1.w + t2.w + t3.w;
        }
    }

    #pragma unroll
    for (int c = 0; c < 4; ++c) {
        const int ci = gchunk * 16 + wave * 4 + c;
        const float4* f4 = (const float4*)(i_features + ((size_t)gfm * CIN + ci) * HW + gsp * SPPX);
        float s0 = 0.f, s1 = 0.f, s2 = 0.f;
        #pragma unroll
        for (int k = 0; k < 4; ++k) {
            const float4 v = f4[lane + 64 * k];
            s0 += v.x * a[0][k].x + v.y * a[0][k].y + v.z * a[0][k].z + v.w * a[0][k].w;
            s1 += v.x * a[1][k].x + v.y * a[1][k].y + v.z * a[1][k].z + v.w * a[1][k].w;
            s2 += v.x * a[2][k].x + v.y * a[2][k].y + v.z * a[2][k].z + v.w * a[2][k].w;
        }
        #pragma unroll
        for (int off = 32; off > 0; off >>= 1) {
            s0 += __shfl_down(s0, off, 64);
            s1 += __shfl_down(s1, off, 64);
            s2 += __shfl_down(s2, off, 64);
        }
        if (lane == 0) {
            gl[0 * 16 + wave * 4 + c] = s0;
            gl[1 * 16 + wave * 4 + c] = s1;
            gl[2 * 16 + wave * 4 + c] = s2;
        }
    }
    __syncthreads();

    // epilogue: out[m, o] += sum_q gl[m][q] * WT[chunk*16+q, o] / 4096
    const int o = tid;
    float acc0 = 0.f, acc1 = 0.f, acc2 = 0.f;
    #pragma unroll
    for (int q = 0; q < 16; ++q) {
        const float wv = WT[(size_t)(gchunk * 16 + q) * DD + o];  // coalesced
        acc0 += gl[0 * 16 + q] * wv;
        acc1 += gl[1 * 16 + q] * wv;
        acc2 += gl[2 * 16 + q] * wv;
    }
    const float inv = 1.f / 4096.f;
    atomicAdd(&out[(size_t)(gm0 + 0) * DD + o], acc0 * inv);
    atomicAdd(&out[(size_t)(gm0 + 1) * DD + o], acc1 * inv);
    atomicAdd(&out[(size_t)(gm0 + 2) * DD + o], acc2 * inv);

    // bias (once per m)
    if (gchunk == 0 && gsp == 0) {
        #pragma unroll
        for (int j = 0; j < 3; ++j) {
            const int m = gm0 + j;
            const float Sm = (Sg4[m * NSP + 0] + Sg4[m * NSP + 1] +
                              Sg4[m * NSP + 2] + Sg4[m * NSP + 3]) * inv;
            atomicAdd(&out[(size_t)m * DD + tid], bfold[tid] * Sm + b_dc[tid]);
        }
    }
}

// ===========================================================================
// Cooperative fused kernel: 512 blocks x 256 thr (ample coop-occupancy margin
// at <=128 VGPR / 16.4 KB LDS -> runtime certifies >=4 blocks/CU >= 1024).
// ===========================================================================
__global__ __launch_bounds__(256, 4) void k_fused(
    const float* __restrict__ i_features,
    const float* __restrict__ p_motions,
    const float* __restrict__ W_emb,
    const float* __restrict__ b_emb,
    const float* __restrict__ W_dc,
    const float* __restrict__ b_dc,
    float* __restrict__ Ag4, float* __restrict__ Sg4,
    float* __restrict__ WT, float* __restrict__ bfold,
    float* __restrict__ out)
{
    __shared__ float Al[HW];     // scatter map (ph1) / gl[3][16] (ph2)
    __shared__ float red[4];
    const int tid = threadIdx.x;
    const int bid = blockIdx.x;
    const int wave = tid >> 6, lane = tid & 63;

    if (bid < M_TOTAL * NSP) {
        scatter_block(p_motions, Ag4, Sg4, Al, red, bid >> 2, bid & 3, tid);
    } else if (bid < M_TOTAL * NSP + DD) {
        fold_block(W_emb, b_emb, W_dc, WT, bfold, out, Al, red,
                   bid - M_TOTAL * NSP, tid);
    }

    cg::this_grid().sync();

    #pragma unroll
    for (int r = 0; r < 2; ++r) {
        const int u = bid + r * 512;
        gather_unit(i_features, Ag4, Sg4, WT, bfold, b_dc, out,
                    Al, u, tid, wave, lane);
        __syncthreads();   // gl (in Al) reused next iteration
    }
}

// ===========================================================================
// Fallback path (proven R5 kernels) — used only if coop launch is rejected.
// ===========================================================================
__global__ __launch_bounds__(256) void k_pre(
    const float* __restrict__ p_motions,
    const float* __restrict__ W_emb,
    const float* __restrict__ b_emb,
    const float* __restrict__ W_dc,
    float* __restrict__ Ag4, float* __restrict__ Sg4,
    float* __restrict__ WT, float* __restrict__ bfold,
    float* __restrict__ out)
{
    __shared__ float Al[HW];
    __shared__ float red[4];
    const int tid = threadIdx.x;
    const int bid = blockIdx.x;
    if (bid < M_TOTAL * NSP)
        scatter_block(p_motions, Ag4, Sg4, Al, red, bid >> 2, bid & 3, tid);
    else
        fold_block(W_emb, b_emb, W_dc, WT, bfold, out, Al, red,
                   bid - M_TOTAL * NSP, tid);
}

__global__ __launch_bounds__(256, 4) void k_gather_out(
    const float* __restrict__ i_features,
    const float* __restrict__ Ag4,
    const float* __restrict__ Sg4,
    const float* __restrict__ WT,
    const float* __restrict__ bfold,
    const float* __restrict__ b_dc,
    float* __restrict__ out)
{
    __shared__ float gl[48];
    const int tid = threadIdx.x;
    const int wave = tid >> 6, lane = tid & 63;
    const int u = (blockIdx.x << 6) | (blockIdx.y << 2) | blockIdx.z;
    gather_unit(i_features, Ag4, Sg4, WT, bfold, b_dc, out,
                gl, u, tid, wave, lane);
}

// ===========================================================================
extern "C" void kernel_launch(void* const* d_in, const int* in_sizes, int n_in,
                              void* d_out, int out_size, void* d_ws, size_t ws_size,
                              hipStream_t stream) {
    // setup_inputs order: imgs, i_features, p_motions, W_emb, b_emb, W_dc, b_dc
    const float* i_features = (const float*)d_in[1];
    const float* p_motions  = (const float*)d_in[2];
    const float* W_emb      = (const float*)d_in[3];
    const float* b_emb      = (const float*)d_in[4];
    const float* W_dc       = (const float*)d_in[5];
    const float* b_dc       = (const float*)d_in[6];
    float* out = (float*)d_out;

    float* ws = (float*)d_ws;
    float* Ag4   = ws;                                   // 48*4*4096 = 786432
    float* Sg4   = Ag4 + (size_t)M_TOTAL * NSP * HW;     // 192 (pad 256)
    float* WT    = Sg4 + 256;                            // 65536
    float* bfold = WT + 65536;                           // 256

    void* args[] = {
        (void*)&i_features, (void*)&p_motions, (void*)&W_emb, (void*)&b_emb,
        (void*)&W_dc, (void*)&b_dc,
        (void*)&Ag4, (void*)&Sg4, (void*)&WT, (void*)&bfold, (void*)&out
    };
    hipError_t e = hipLaunchCooperativeKernel((const void*)k_fused,
                                              dim3(512), dim3(256),
                                              args, 0, stream);
    if (e != hipSuccess) {
        (void)hipGetLastError();   // clear sticky error, take proven 2-kernel path
        k_pre<<<M_TOTAL * NSP + DD, 256, 0, stream>>>(
            p_motions, W_emb, b_emb, W_dc, Ag4, Sg4, WT, bfold, out);
        dim3 g2(16, 16, NSP);
        k_gather_out<<<g2, 256, 0, stream>>>(
            i_features, Ag4, Sg4, WT, bfold, b_dc, out);
    }
}

// Round 8
// 161.442 us; speedup vs baseline: 1.5445x; 1.5445x over previous
//
#include <hip/hip_runtime.h>
#include <math.h>

#define HW 4096
#define CIN 256
#define DD 256
#define M_TOTAL 48
#define NSP 4
#define SPPX (HW / NSP)     // 1024 px per scatter slice
#define NSUB 8              // gather sub-slices
#define SUBPX (HW / NSUB)   // 512 px per gather block

// ---------------------------------------------------------------------------
// K1 (448 blocks x 256 thr):
//   blocks 0..191   : (m, sp) flow + bilinear tap scatter into private LDS
//                     map, written whole to Ag4[m][sp] (no memset/global
//                     atomics). Partial sum -> Sg4[m][sp].
//   blocks 192..447 : fold WT[ci][o] = sum_k W_dc[o,k]*W_emb[k,ci]
//                     (transposed store) + bfold[o] = W_dc[o,:].b_emb
//                     + zero a 48-float slice of out.
// ---------------------------------------------------------------------------
__global__ __launch_bounds__(256) void k_pre(
    const float* __restrict__ p_motions,
    const float* __restrict__ W_emb,
    const float* __restrict__ b_emb,
    const float* __restrict__ W_dc,
    float* __restrict__ Ag4,     // [48][4][4096] partial maps
    float* __restrict__ Sg4,     // [48][4]
    float* __restrict__ WT,      // [256][256] = WT[ci*256+o]
    float* __restrict__ bfold,   // [256]
    float* __restrict__ out)     // zeroed here
{
    const int tid = threadIdx.x;
    const int bid = blockIdx.x;

    if (bid < M_TOTAL * NSP) {
        // ---------------- flow + scatter ----------------
        __shared__ float Al[HW];     // 16 KB private partial map
        __shared__ float red[4];
        const int m = bid >> 2;
        const int sp = bid & 3;
        const float4* p0 = (const float4*)(p_motions + (size_t)m * 2 * 65536); // dy
        const float4* p1 = p0 + 65536 / 4;                                     // dx

        for (int i = tid; i < HW; i += 256) Al[i] = 0.f;
        __syncthreads();

        #pragma unroll
        for (int ii = 0; ii < SPPX / 256; ++ii) {
            const int i = ii * 256 + tid;          // 0..1023 within slab
            const int y = sp * 16 + (i >> 6);
            const int x = i & 63;
            const int r1 = 4 * y + 1, r2 = 4 * y + 2;
            // taps at cols 4x+1,4x+2 = elements .y/.z of float4 index x
            const float4 v10 = p0[r1 * 64 + x];
            const float4 v20 = p0[r2 * 64 + x];
            const float4 v11 = p1[r1 * 64 + x];
            const float4 v21 = p1[r2 * 64 + x];
            const float fy = (v10.y + v10.z + v20.y + v20.z) * 0.0625f; // avg*0.25
            const float fx = (v11.y + v11.z + v21.y + v21.z) * 0.0625f;

            const float yy = (float)y + fy;
            const float xx = (float)x + fx;
            const float y0f = floorf(yy), x0f = floorf(xx);
            const float wy = yy - y0f, wx = xx - x0f;
            const int iy0 = (int)y0f, ix0 = (int)x0f;
            const int iy1 = iy0 + 1, ix1 = ix0 + 1;
            const float w00 = (1.f - wy) * (1.f - wx);
            const float w01 = (1.f - wy) * wx;
            const float w10 = wy * (1.f - wx);
            const float w11 = wy * wx;
            const bool y0ok = (iy0 >= 0) & (iy0 < 64);
            const bool y1ok = (iy1 >= 0) & (iy1 < 64);
            const bool x0ok = (ix0 >= 0) & (ix0 < 64);
            const bool x1ok = (ix1 >= 0) & (ix1 < 64);
            if (y0ok & x0ok) atomicAdd(&Al[iy0 * 64 + ix0], w00);
            if (y0ok & x1ok) atomicAdd(&Al[iy0 * 64 + ix1], w01);
            if (y1ok & x0ok) atomicAdd(&Al[iy1 * 64 + ix0], w10);
            if (y1ok & x1ok) atomicAdd(&Al[iy1 * 64 + ix1], w11);
        }
        __syncthreads();

        // write whole partial map (plain float4 stores) + partial sum
        const float4* Al4 = (const float4*)Al;
        float4* dst = (float4*)(Ag4 + (size_t)(m * NSP + sp) * HW);
        float part = 0.f;
        #pragma unroll
        for (int i = tid; i < HW / 4; i += 256) {
            const float4 v = Al4[i];
            dst[i] = v;
            part += v.x + v.y + v.z + v.w;
        }
        for (int off = 32; off > 0; off >>= 1) part += __shfl_down(part, off, 64);
        if ((tid & 63) == 0) red[tid >> 6] = part;
        __syncthreads();
        if (tid == 0) Sg4[m * NSP + sp] = red[0] + red[1] + red[2] + red[3];
    } else {
        // ---------------- weight fold + out zeroing ----------------
        __shared__ float wdc[256];
        __shared__ float red2[4];
        const int o = bid - M_TOTAL * NSP;     // 0..255
        wdc[tid] = W_dc[(size_t)o * 256 + tid];
        if (tid < 48) out[(size_t)o * 48 + tid] = 0.f;  // 256*48 = 48*256 floats
        __syncthreads();
        float acc = 0.f;
        #pragma unroll 8
        for (int k = 0; k < 256; ++k)
            acc += wdc[k] * W_emb[(size_t)k * 256 + tid];   // coalesced rows
        WT[(size_t)tid * 256 + o] = acc;                    // transposed store

        float pb = wdc[tid] * b_emb[tid];
        for (int off = 32; off > 0; off >>= 1) pb += __shfl_down(pb, off, 64);
        if ((tid & 63) == 0) red2[tid >> 6] = pb;
        __syncthreads();
        if (tid == 0) bfold[o] = red2[0] + red2[1] + red2[2] + red2[3];
    }
}

// ---------------------------------------------------------------------------
// K2: gather + epilogue fused. Grid (fm=16, chunk=16, sub=8) = 2048 blocks
// (8 blocks/CU, 32 waves/CU for latency hiding on the i_features stream).
// Each block: sum the 4 partial A maps over its 512-px window into registers
// (a[3][2]), dot with 16 channels of i_features (coalesced float4), wave-
// reduce, apply the 16x256 WT slice, atomicAdd into out.
// Bias added by (chunk==0, sub==0) blocks.
// ---------------------------------------------------------------------------
__global__ __launch_bounds__(256, 4) void k_gather_out(
    const float* __restrict__ i_features,
    const float* __restrict__ Ag4,
    const float* __restrict__ Sg4,
    const float* __restrict__ WT,
    const float* __restrict__ bfold,
    const float* __restrict__ b_dc,
    float* __restrict__ out)
{
    __shared__ float gl[3][16];
    const int fm = blockIdx.x;     // 0..15
    const int chunk = blockIdx.y;  // 0..15
    const int sub = blockIdx.z;    // 0..7
    const int tid = threadIdx.x;
    const int wave = tid >> 6, lane = tid & 63;
    const int m0 = fm * 3;
    const int off4 = sub * (SUBPX / 4);   // float4 offset of this window

    // sum the 4 partial A maps over this 512-px window into registers
    float4 a[3][2];
    #pragma unroll
    for (int j = 0; j < 3; ++j) {
        const float4* P0 = (const float4*)(Ag4 + ((size_t)((m0 + j) * NSP + 0)) * HW) + off4;
        const float4* P1 = (const float4*)(Ag4 + ((size_t)((m0 + j) * NSP + 1)) * HW) + off4;
        const float4* P2 = (const float4*)(Ag4 + ((size_t)((m0 + j) * NSP + 2)) * HW) + off4;
        const float4* P3 = (const float4*)(Ag4 + ((size_t)((m0 + j) * NSP + 3)) * HW) + off4;
        #pragma unroll
        for (int k = 0; k < 2; ++k) {
            const float4 t0 = P0[lane + 64 * k];
            const float4 t1 = P1[lane + 64 * k];
            const float4 t2 = P2[lane + 64 * k];
            const float4 t3 = P3[lane + 64 * k];
            a[j][k].x = t0.x + t1.x + t2.x + t3.x;
            a[j][k].y = t0.y + t1.y + t2.y + t3.y;
            a[j][k].z = t0.z + t1.z + t2.z + t3.z;
            a[j][k].w = t0.w + t1.w + t2.w + t3.w;
        }
    }

    #pragma unroll
    for (int c = 0; c < 4; ++c) {
        const int ci = chunk * 16 + wave * 4 + c;
        const float4* f4 = (const float4*)(i_features + ((size_t)fm * CIN + ci) * HW) + off4;
        float s0 = 0.f, s1 = 0.f, s2 = 0.f;
        #pragma unroll
        for (int k = 0; k < 2; ++k) {
            const float4 v = f4[lane + 64 * k];
            s0 += v.x * a[0][k].x + v.y * a[0][k].y + v.z * a[0][k].z + v.w * a[0][k].w;
            s1 += v.x * a[1][k].x + v.y * a[1][k].y + v.z * a[1][k].z + v.w * a[1][k].w;
            s2 += v.x * a[2][k].x + v.y * a[2][k].y + v.z * a[2][k].z + v.w * a[2][k].w;
        }
        #pragma unroll
        for (int off = 32; off > 0; off >>= 1) {
            s0 += __shfl_down(s0, off, 64);
            s1 += __shfl_down(s1, off, 64);
            s2 += __shfl_down(s2, off, 64);
        }
        if (lane == 0) {
            gl[0][wave * 4 + c] = s0;
            gl[1][wave * 4 + c] = s1;
            gl[2][wave * 4 + c] = s2;
        }
    }
    __syncthreads();

    // epilogue: out[m, o] += sum_q gl[m][q] * WT[chunk*16+q, o] / 4096
    const int o = tid;
    float acc0 = 0.f, acc1 = 0.f, acc2 = 0.f;
    #pragma unroll
    for (int q = 0; q < 16; ++q) {
        const float wv = WT[(size_t)(chunk * 16 + q) * DD + o];  // coalesced
        acc0 += gl[0][q] * wv;
        acc1 += gl[1][q] * wv;
        acc2 += gl[2][q] * wv;
    }
    const float inv = 1.f / 4096.f;
    atomicAdd(&out[(size_t)(m0 + 0) * DD + o], acc0 * inv);
    atomicAdd(&out[(size_t)(m0 + 1) * DD + o], acc1 * inv);
    atomicAdd(&out[(size_t)(m0 + 2) * DD + o], acc2 * inv);

    // bias (once per m): blocks with chunk==0 && sub==0
    if (chunk == 0 && sub == 0) {
        #pragma unroll
        for (int j = 0; j < 3; ++j) {
            const int m = m0 + j;
            const float Sm = (Sg4[m * NSP + 0] + Sg4[m * NSP + 1] +
                              Sg4[m * NSP + 2] + Sg4[m * NSP + 3]) * inv;
            atomicAdd(&out[(size_t)m * DD + tid], bfold[tid] * Sm + b_dc[tid]);
        }
    }
}

// ---------------------------------------------------------------------------
extern "C" void kernel_launch(void* const* d_in, const int* in_sizes, int n_in,
                              void* d_out, int out_size, void* d_ws, size_t ws_size,
                              hipStream_t stream) {
    // setup_inputs order: imgs, i_features, p_motions, W_emb, b_emb, W_dc, b_dc
    const float* i_features = (const float*)d_in[1];
    const float* p_motions  = (const float*)d_in[2];
    const float* W_emb      = (const float*)d_in[3];
    const float* b_emb      = (const float*)d_in[4];
    const float* W_dc       = (const float*)d_in[5];
    const float* b_dc       = (const float*)d_in[6];
    float* out = (float*)d_out;

    float* ws = (float*)d_ws;
    float* Ag4   = ws;                                   // 48*4*4096 = 786432
    float* Sg4   = Ag4 + (size_t)M_TOTAL * NSP * HW;     // 192 (pad 256)
    float* WT    = Sg4 + 256;                            // 65536
    float* bfold = WT + 65536;                           // 256
    // total ~3.25 MB

    k_pre<<<M_TOTAL * NSP + DD, 256, 0, stream>>>(p_motions, W_emb, b_emb, W_dc,
                                                  Ag4, Sg4, WT, bfold, out);
    dim3 g2(16, 16, NSUB);
    k_gather_out<<<g2, 256, 0, stream>>>(i_features, Ag4, Sg4, WT, bfold, b_dc, out);
}